// Round 1
// baseline (507.598 us; speedup 1.0000x reference)
//
#include <hip/hip_runtime.h>

// Problem constants (fixed by setup_inputs): B=64, H=W=1024, p=64.
#define BATCH     64
#define HEIGHT    1024
#define WIDTH     1024
#define PSZ       64
#define NPH       16              // HEIGHT / PSZ
#define NPW       16              // WIDTH / PSZ
#define HALF_ROWS 32              // rows per half-strip
#define NBLK      (BATCH * NPH * 2)   // 2048 blocks

// Kernel 1: one block per (image, patch-row, half). 2048 blocks x 256 threads
// (= 32 waves/CU, up from 16). Thread t covers columns 4t..4t+3 for 32
// consecutive rows; each iteration the block reads two fully-contiguous 4 KB
// rows (o and t). The row-loop START PHASE is rotated by a per-block hash so
// blocks launched together do not sweep HBM channels in lockstep (each block's
// base is a multiple of 128 KB; identical phase => congruent address sets
// modulo every power-of-two interleave granularity -> convoy hotspotting).
// Patch identity is tid>>4; a width-16 shuffle reduce yields the 16 partial
// patch sums (over 32 rows), written to part[img*512 + half*256 + prow*16 + pcol].
__global__ __launch_bounds__(256) void patch_halfstrip_kernel(
    const float* __restrict__ out_p, const float* __restrict__ tgt_p,
    float* __restrict__ part)
{
    const int blk  = blockIdx.x;           // [0, 2048)
    const int img  = blk >> 5;
    const int rem  = blk & 31;
    const int prow = rem >> 1;
    const int half = rem & 1;

    const size_t base = (size_t)img * (HEIGHT * (size_t)WIDTH)
                      + (size_t)prow * PSZ * WIDTH
                      + (size_t)half * HALF_ROWS * WIDTH
                      + (size_t)threadIdx.x * 4;

    const float4* __restrict__ po = reinterpret_cast<const float4*>(out_p + base);
    const float4* __restrict__ pt = reinterpret_cast<const float4*>(tgt_p + base);
    const int row_stride_f4 = WIDTH / 4;   // 256 float4 per row

    // per-block start phase in [0,32): top-5 bits of a golden-ratio hash
    const int r0 = (int)(((unsigned)blk * 2654435761u) >> 27);

    float s0 = 0.f, s1 = 0.f;
#pragma unroll 8
    for (int i = 0; i < HALF_ROWS; ++i) {
        const int r = (i + r0) & (HALF_ROWS - 1);
        const float4 a = po[(size_t)r * row_stride_f4];
        const float4 c = pt[(size_t)r * row_stride_f4];
        s0 += fabsf(a.x - c.x) + fabsf(a.y - c.y);
        s1 += fabsf(a.z - c.z) + fabsf(a.w - c.w);
    }
    float s = s0 + s1;

    // width-16 segment reduce: lanes with (tid&15)==0 hold half-patch sums
#pragma unroll
    for (int off = 8; off > 0; off >>= 1)
        s += __shfl_down(s, off, 16);

    if ((threadIdx.x & 15) == 0) {
        const int pcol = threadIdx.x >> 4;
        part[(size_t)img * (NPH * NPW * 2) + half * (NPH * NPW)
             + prow * NPW + pcol] = s;     // raw sum over 32x64 elems
    }
}

// Kernel 2: single 1024-thread block. part[] holds 64 images x 2 halves x
// 16 prow x 16 pcol raw sums (128 KB). Thread (img = t>>4, j = t&15) combines
// the two halves for prow=j (4+4 coalesced float4 loads), takes max over its
// 16 pcol, width-16 shuffle-max -> per-image max on j==0, scale by 1/4096,
// then wave-sum + LDS across 16 waves -> mean over 64 images.
__global__ __launch_bounds__(1024) void final_reduce_kernel(
    const float* __restrict__ part, float* __restrict__ result)
{
    const int t   = threadIdx.x;
    const int img = t >> 4;
    const int j   = t & 15;                // prow handled by this thread

    // img stride = 512 floats = 128 float4; half stride = 256 floats = 64 float4
    const float4* __restrict__ p =
        reinterpret_cast<const float4*>(part) + img * 128 + j * 4;

    float m = 0.0f;                        // patch sums are >= 0 (ref maxes with 0)
#pragma unroll
    for (int q = 0; q < 4; ++q) {
        const float4 a = p[q];             // half 0
        const float4 b = p[64 + q];        // half 1
        m = fmaxf(m, fmaxf(fmaxf(a.x + b.x, a.y + b.y),
                           fmaxf(a.z + b.z, a.w + b.w)));
    }

    // max over the 16 prow-threads of this image
#pragma unroll
    for (int off = 8; off > 0; off >>= 1)
        m = fmaxf(m, __shfl_down(m, off, 16));

    float contrib = (j == 0) ? m * (1.0f / (PSZ * PSZ)) : 0.0f;
#pragma unroll
    for (int off = 32; off > 0; off >>= 1)
        contrib += __shfl_down(contrib, off, 64);

    __shared__ float lds[16];
    if ((t & 63) == 0) lds[t >> 6] = contrib;
    __syncthreads();
    if (t == 0) {
        float acc = 0.f;
#pragma unroll
        for (int i = 0; i < 16; ++i) acc += lds[i];
        result[0] = acc * (1.0f / BATCH);
    }
}

extern "C" void kernel_launch(void* const* d_in, const int* in_sizes, int n_in,
                              void* d_out, int out_size, void* d_ws, size_t ws_size,
                              hipStream_t stream) {
    const float* out_p = (const float*)d_in[0];
    const float* tgt_p = (const float*)d_in[1];
    // d_in[2] is patch_size (=64), baked into kernel constants.
    float* part   = (float*)d_ws;          // 2048*16 floats = 128 KB scratch
    float* result = (float*)d_out;

    patch_halfstrip_kernel<<<NBLK, 256, 0, stream>>>(out_p, tgt_p, part);
    final_reduce_kernel<<<1, 1024, 0, stream>>>(part, result);
}

// Round 2
// 494.678 us; speedup vs baseline: 1.0261x; 1.0261x over previous
//
#include <hip/hip_runtime.h>

// Problem constants (fixed by setup_inputs): B=64, H=W=1024, p=64.
#define BATCH   64
#define HEIGHT  1024
#define WIDTH   1024
#define PSZ     64
#define NPH     16              // HEIGHT / PSZ
#define NPW     16              // WIDTH / PSZ
#define NROWS   (BATCH * HEIGHT)        // 65536 rows of 1024 floats
#define NBLK    2048                    // 2048 blk x 4 waves = 8192 waves = all-resident
#define K_STEPS (NROWS / NBLK)          // 32 rows per block

// clang native vector so __builtin_nontemporal_load applies cleanly
using f32x4 = __attribute__((ext_vector_type(4))) float;

// Kernel 1: fill-mimicking sweep. Block b, step k reads row k*2048 + b from
// both buffers, so the grid's instantaneous footprint is ONE contiguous 8 MiB
// span sweeping through each buffer (the access pattern the harness fill
// demonstrably drives at 6.7 TB/s), instead of 2048 static 128 KB windows.
// Loads are non-temporal (read-once stream; skip L2/L3 allocation).
// Thread t covers columns 4t..4t+3 (pcol = t>>4); a width-16 shuffle reduce
// yields 16 per-row per-pcol sums, written to rowsum[row*16 + pcol] (4 MB).
__global__ __launch_bounds__(256) void rowsum_sweep_kernel(
    const float* __restrict__ out_p, const float* __restrict__ tgt_p,
    float* __restrict__ rowsum)
{
    const int tid  = threadIdx.x;
    const int pcol = tid >> 4;
    const f32x4* __restrict__ po = reinterpret_cast<const f32x4*>(out_p);
    const f32x4* __restrict__ pt = reinterpret_cast<const f32x4*>(tgt_p);

#pragma unroll 4
    for (int k = 0; k < K_STEPS; ++k) {
        const int row = (k << 11) + (int)blockIdx.x;      // k*2048 + b
        const size_t idx = (size_t)row * (WIDTH / 4) + tid;
        const f32x4 a = __builtin_nontemporal_load(po + idx);
        const f32x4 c = __builtin_nontemporal_load(pt + idx);
        float s = fabsf(a[0] - c[0]) + fabsf(a[1] - c[1])
                + fabsf(a[2] - c[2]) + fabsf(a[3] - c[3]);
        // width-16 segment reduce: lane (tid&15)==0 holds the pcol sum
#pragma unroll
        for (int off = 8; off > 0; off >>= 1)
            s += __shfl_down(s, off, 16);
        if ((tid & 15) == 0)
            rowsum[(size_t)row * NPW + pcol] = s;         // 64 B per row, contiguous
    }
}

// Kernel 2: one block per image. rowsum is [img][prow][rip][pcol] (64 KB per
// image, L2/L3-resident). Thread t owns patch (prow = t>>4, pcol = t&15):
// serial sum over the 64 row-partials -> patch sum; block-wide max over the
// 256 patches; scale by 1/4096 -> img_max[img].
__global__ __launch_bounds__(256) void img_max_kernel(
    const float* __restrict__ rowsum, float* __restrict__ img_max)
{
    const int img = blockIdx.x;            // [0, 64)
    const int t   = threadIdx.x;
    const float* __restrict__ base =
        rowsum + ((size_t)img * NPH + (t >> 4)) * (PSZ * NPW) + (t & 15);

    float s = 0.0f;
#pragma unroll
    for (int rip = 0; rip < PSZ; ++rip)
        s += base[(size_t)rip * NPW];

    // max across the 256 patch-threads (patch sums >= 0; ref maxes with 0)
    float m = s;
#pragma unroll
    for (int off = 32; off > 0; off >>= 1)
        m = fmaxf(m, __shfl_down(m, off, 64));

    __shared__ float lds[4];
    if ((t & 63) == 0) lds[t >> 6] = m;
    __syncthreads();
    if (t == 0) {
        float v = fmaxf(fmaxf(lds[0], lds[1]), fmaxf(lds[2], lds[3]));
        img_max[img] = v * (1.0f / (PSZ * PSZ));
    }
}

// Kernel 3: single wave, mean over the 64 image maxima.
__global__ __launch_bounds__(64) void final_mean_kernel(
    const float* __restrict__ img_max, float* __restrict__ result)
{
    float v = img_max[threadIdx.x];
#pragma unroll
    for (int off = 32; off > 0; off >>= 1)
        v += __shfl_down(v, off, 64);
    if (threadIdx.x == 0)
        result[0] = v * (1.0f / BATCH);
}

extern "C" void kernel_launch(void* const* d_in, const int* in_sizes, int n_in,
                              void* d_out, int out_size, void* d_ws, size_t ws_size,
                              hipStream_t stream) {
    const float* out_p = (const float*)d_in[0];
    const float* tgt_p = (const float*)d_in[1];
    // d_in[2] is patch_size (=64), baked into kernel constants.
    float* rowsum  = (float*)d_ws;                         // 65536*16 floats = 4 MB
    float* img_max = (float*)d_ws + (size_t)NROWS * NPW;   // + 64 floats
    float* result  = (float*)d_out;

    rowsum_sweep_kernel<<<NBLK, 256, 0, stream>>>(out_p, tgt_p, rowsum);
    img_max_kernel<<<BATCH, 256, 0, stream>>>(rowsum, img_max);
    final_mean_kernel<<<1, 64, 0, stream>>>(img_max, result);
}